// Round 5
// baseline (180.182 us; speedup 1.0000x reference)
//
#include <hip/hip_runtime.h>
#include <stdint.h>

typedef float f32x4 __attribute__((ext_vector_type(4)));
typedef __bf16 bf16x8 __attribute__((ext_vector_type(8)));
typedef __bf16 bf16x2 __attribute__((ext_vector_type(2)));

#define NROW 16384
#define DM   1024
#define HID  128
#define K1   8192   // DM*8 features
#define K2   1024   // HID*8 features

__device__ __forceinline__ unsigned short f2bf(float f) {
  unsigned u = __builtin_bit_cast(unsigned, f);
  u += 0x7fffu + ((u >> 16) & 1u);
  return (unsigned short)(u >> 16);
}

__device__ __forceinline__ uint32_t pk2(float lo, float hi) {
  bf16x2 v;
  v[0] = (__bf16)lo;           // compiler pairs these into v_cvt_pk_bf16_f32
  v[1] = (__bf16)hi;
  return __builtin_bit_cast(uint32_t, v);
}

__device__ __forceinline__ void g2l16(const void* g, void* l) {
  __builtin_amdgcn_global_load_lds(
      (const __attribute__((address_space(1))) unsigned int*)g,
      (__attribute__((address_space(3))) unsigned int*)l, 16, 0, 0);
}

// 8-feature expansion: [silu_hi, B0..B5, silu_lo].
// Uniform cubic B-spline, knots g_j=(j-3)*(2/3)-1 (j=0..9). Cell c=floor((v+3)*1.5),
// u=frac. Active bases B_g = P_{c-g}, g=c-3..c. Scatter [p3,p2,p1,p0] (bf16 slots,
// slot0=p3) into slots 1..6 of a 128-bit value via shift by (c-2)*16 bits.
// c clamped to [-1,9]: out-of-grid -> all-zero B (matches reference recursion).
__device__ __forceinline__ bf16x8 expand8(float v) {
  const float t = (v + 3.0f) * 1.5f;
  const float cf = floorf(t);
  const float u = t - cf;
  int c = (int)cf;
  c = c < -1 ? -1 : c;
  c = c > 9 ? 9 : c;
  const float u2 = u * u, u3 = u2 * u, omu = 1.0f - u;
  const float p0 = u3 * (1.0f / 6.0f);
  const float p1 = (1.0f / 6.0f) + 0.5f * u + 0.5f * u2 - 0.5f * u3;
  const float p2 = (4.0f / 6.0f) - u2 + 0.5f * u3;
  const float p3 = omu * omu * omu * (1.0f / 6.0f);
  const uint64_t W = (uint64_t)pk2(p3, p2) | ((uint64_t)pk2(p1, p0) << 32);
  const int sa = (c - 2) * 16;                 // in [-48, 112]
  const int sl = sa & 63;
  const uint64_t t1 = W << sl;
  const uint64_t t2 = (W >> (63 - sl)) >> 1;   // == W >> (64-sl), defined at sl=0
  const uint64_t t3 = W >> ((-sa) & 63);
  const uint64_t L = sa < 0 ? t3 : (sa < 64 ? t1 : 0);
  const uint64_t H = sa < 0 ? 0  : (sa < 64 ? t2 : t1);
  const float s = v * __frcp_rn(1.0f + __expf(-v));   // silu
  const uint32_t sh = (uint32_t)__builtin_bit_cast(unsigned short, (__bf16)s);
  const float shf = __builtin_bit_cast(float, sh << 16);
  const uint32_t slo = (uint32_t)__builtin_bit_cast(unsigned short, (__bf16)(s - shf));
  const uint32_t w0 = ((uint32_t)L & 0xffff0000u) | sh;
  const uint32_t w1 = (uint32_t)(L >> 32);
  const uint32_t w2 = (uint32_t)H;
  const uint32_t w3 = ((uint32_t)(H >> 32) & 0xffffu) | (slo << 16);
  union { uint4 q; bf16x8 b; } r;
  r.q = (uint4){w0, w1, w2, w3};
  return r.b;
}

// ---- weight prep: W1T[o][i*8+c] bf16, c0=scale_base (dup at c7), c1..6=coef*sp
__global__ void kan_prep_w1(const float* __restrict__ c1, const float* __restrict__ sb1,
                            const float* __restrict__ sp1, unsigned short* __restrict__ w1t) {
  const int t = blockIdx.x * 256 + threadIdx.x;     // 131072 threads
  const int o = t >> 10, i = t & 1023;
  const float sb = sb1[i * HID + o], sp = sp1[i * HID + o];
  const float* cf = c1 + (size_t)(i * HID + o) * 6;
  union { uint4 u; unsigned short h[8]; } r;
  const unsigned short b = f2bf(sb);
  r.h[0] = b; r.h[7] = b;
#pragma unroll
  for (int g = 0; g < 6; ++g) r.h[g + 1] = f2bf(cf[g] * sp);
  *(uint4*)(w1t + (size_t)o * K1 + i * 8) = r.u;
}

__global__ void kan_prep_w2(const float* __restrict__ c2, const float* __restrict__ sb2,
                            const float* __restrict__ sp2, unsigned short* __restrict__ w2t) {
  const int t = blockIdx.x * 256 + threadIdx.x;     // 131072 threads
  const int o = t >> 7, i = t & 127;
  const float sb = sb2[i * DM + o], sp = sp2[i * DM + o];
  const float* cf = c2 + (size_t)(i * DM + o) * 6;
  union { uint4 u; unsigned short h[8]; } r;
  const unsigned short b = f2bf(sb);
  r.h[0] = b; r.h[7] = b;
#pragma unroll
  for (int g = 0; g < 6; ++g) r.h[g + 1] = f2bf(cf[g] * sp);
  *(uint4*)(w2t + (size_t)o * K2 + i * 8) = r.u;
}

// ---- layer 1: fused expand(x) -> GEMM partial -> yp[kh]
// BM=64, BN=128(full), BK=64, K-split 2. grid 512 = 256 mt x 2 kh, 512 thr
// -> 2 blocks/CU (phase-offset barriers). 8 waves: wk=w>>2 K-half, wave-tile
// 32x64 (acc 2x4). A (expanded x) in LDS dbuf 2x8KB swizzled; B (W1T, L2-hot)
// direct to VGPRs, double-buffered. 1 expansion/thread/K-tile.
__global__ __launch_bounds__(512, 4) void kan_gemm1(
    const float* __restrict__ x, const unsigned short* __restrict__ w1t,
    float* __restrict__ yp) {
  __shared__ __align__(16) char lds[32768];   // A dbuf = 16KB; epilogue reduce = 32KB
  const int tid = threadIdx.x;
  const int lane = tid & 63, w = tid >> 6;
  const int wk = w >> 2, wm = (w >> 1) & 1, wn = w & 1;
  const int mt = blockIdx.x >> 1, kh = blockIdx.x & 1;
  const int m0 = mt * 64;
  const int arow = tid >> 3, acol = tid & 7;

  f32x4 acc[2][4];
#pragma unroll
  for (int a = 0; a < 2; ++a)
#pragma unroll
    for (int b = 0; b < 4; ++b) acc[a][b] = (f32x4){0.f, 0.f, 0.f, 0.f};

  // B fragment pointers (bo row, k-offset within tile); advance by 64 elem/tile
  const int bo = wn * 64 + (lane & 15);
  const unsigned short* bp = w1t + (size_t)bo * K1 + kh * 4096 + wk * 32 + (lane >> 4) * 8;

  // hoisted LDS addresses (thread-constant; buffer toggle = +8192)
  char* wa0 = lds + ((arow * 128 + acol * 16) ^ ((arow & 7) << 4));
  char* wa1 = wa0 + 8192;
  const char* ra0[2];
#pragma unroll
  for (int mi = 0; mi < 2; ++mi) {
    const int row = wm * 32 + mi * 16 + (lane & 15);
    ra0[mi] = lds + ((row * 128 + wk * 64 + (lane >> 4) * 16) ^ ((row & 7) << 4));
  }
  const float* xp = x + (size_t)(m0 + arow) * DM + kh * 512 + acol;

  bf16x8 b0[4], b1[4], af[2];
  float xv;

#define LOADB(dst, kt)                                                        \
  _Pragma("unroll") for (int ni = 0; ni < 4; ++ni)                            \
      dst[ni] = *(const bf16x8*)(bp + (size_t)ni * 16 * K1 + (kt) * 64);

#define MFMA_TILE(bb, roff)                                                   \
  _Pragma("unroll") for (int mi = 0; mi < 2; ++mi)                            \
      af[mi] = *(const bf16x8*)(ra0[mi] + roff);                              \
  _Pragma("unroll") for (int mi = 0; mi < 2; ++mi)                            \
  _Pragma("unroll") for (int ni = 0; ni < 4; ++ni)                            \
      acc[mi][ni] = __builtin_amdgcn_mfma_f32_16x16x32_bf16(af[mi], bb[ni],   \
                                                            acc[mi][ni], 0, 0, 0);

  // prologue
  LOADB(b0, 0);
  *(bf16x8*)wa0 = expand8(xp[0]);
  xv = xp[8];
  __syncthreads();

  for (int kt = 0; kt < 64; kt += 2) {
    LOADB(b1, kt + 1);                       // L2 latency hides under expand VALU
    *(bf16x8*)wa1 = expand8(xv);
    xv = xp[(kt + 2 < 64 ? kt + 2 : 63) * 8];
    MFMA_TILE(b0, 0)
    __syncthreads();
    if (kt + 2 < 64) {
      LOADB(b0, kt + 2);
      *(bf16x8*)wa0 = expand8(xv);
      xv = xp[(kt + 3 < 64 ? kt + 3 : 63) * 8];
    }
    MFMA_TILE(b1, 8192)
    __syncthreads();
  }
#undef LOADB
#undef MFMA_TILE

  // cross-wk reduce via LDS (A buffers dead; 4 waves x 8KB = 32KB)
  if (wk == 1) {
    char* r = lds + (w & 3) * 8192;
#pragma unroll
    for (int mi = 0; mi < 2; ++mi)
#pragma unroll
      for (int ni = 0; ni < 4; ++ni)
        *(f32x4*)(r + (mi * 4 + ni) * 1024 + lane * 16) = acc[mi][ni];
  }
  __syncthreads();
  if (wk == 0) {
    const char* r = lds + w * 8192;
    float* yb = yp + (size_t)kh * NROW * HID;
#pragma unroll
    for (int mi = 0; mi < 2; ++mi)
#pragma unroll
      for (int ni = 0; ni < 4; ++ni) {
        f32x4 o = *(const f32x4*)(r + (mi * 4 + ni) * 1024 + lane * 16);
        o += acc[mi][ni];
        const int col = wn * 64 + ni * 16 + (lane & 15);
#pragma unroll
        for (int rr = 0; rr < 4; ++rr) {
          const int row = wm * 32 + mi * 16 + (lane >> 4) * 4 + rr;
          yb[(size_t)(m0 + row) * HID + col] = o[rr];
        }
      }
  }
}

// ---- combine K-halves + expand y1 -> a2 (bf16 features for layer 2)
__global__ void kan_combine(const float* __restrict__ yp, unsigned short* __restrict__ a2) {
  const size_t i = (size_t)blockIdx.x * 256 + threadIdx.x;   // 2,097,152 threads
  const float v = yp[i] + yp[i + (size_t)NROW * HID];
  bf16x8 u = expand8(v);
  *(bf16x8*)(a2 + i * 8) = u;
}

// ---- layer 2: plain bf16 GEMM (16384x1024) @ (1024x1024)^T -> fp32 out
// BM=BN=128, BK=64, counted-vmcnt pipeline: prefetch stays in flight across
// the barrier (vmcnt(8) = next tile's 8 g2l outstanding), never drain to 0
// in the main loop.
__global__ __launch_bounds__(256, 2) void kan_gemm2(
    const unsigned short* __restrict__ a2, const unsigned short* __restrict__ w2t,
    float* __restrict__ out) {
  __shared__ __align__(16) unsigned short lds[2 * 16384];
  const int tid = threadIdx.x;
  const int lane = tid & 63, w = tid >> 6;
  const int wm = w >> 1, wn = w & 1;
  const int mt = blockIdx.x & 127, nt = blockIdx.x >> 7;  // mt fastest: A-panel sharers on same XCD
  const int m0 = mt * 128, n0 = nt * 128;

  f32x4 acc[4][4];
#pragma unroll
  for (int a = 0; a < 4; ++a)
#pragma unroll
    for (int b = 0; b < 4; ++b) acc[a][b] = (f32x4){0.f, 0.f, 0.f, 0.f};

  auto stage = [&](int kt, int buf) {      // 8 g2l per wave
#pragma unroll
    for (int q = 0; q < 4; ++q) {
      const int r = (w * 4 + q) * 8 + (lane >> 3);
      const int slot = (lane & 7) ^ (lane >> 3);
      g2l16(a2 + (size_t)(m0 + r) * K2 + kt * 64 + slot * 8,
            (char*)lds + buf * 32768 + (w * 4 + q) * 1024);
      g2l16(w2t + (size_t)(n0 + r) * K2 + kt * 64 + slot * 8,
            (char*)lds + buf * 32768 + 16384 + (w * 4 + q) * 1024);
    }
  };

  stage(0, 0);
  for (int kt = 0; kt < 16; ++kt) {
    const int cur = kt & 1;
    if (kt + 1 < 16) {
      stage(kt + 1, cur ^ 1);
      asm volatile("s_waitcnt vmcnt(8)" ::: "memory");   // wait tile kt only
    } else {
      asm volatile("s_waitcnt vmcnt(0)" ::: "memory");
    }
    __builtin_amdgcn_sched_barrier(0);
    __builtin_amdgcn_s_barrier();                        // tile kt in LDS for all waves
    const char* ab = (const char*)lds + cur * 32768;
    const char* bb = ab + 16384;
#pragma unroll
    for (int ks = 0; ks < 2; ++ks) {
      bf16x8 af[4], bfr[4];
#pragma unroll
      for (int mi = 0; mi < 4; ++mi) {
        const int row = wm * 64 + mi * 16 + (lane & 15);
        af[mi] = *(const bf16x8*)(ab + ((row * 128 + ks * 64 + (lane >> 4) * 16) ^ ((row & 7) << 4)));
      }
#pragma unroll
      for (int ni = 0; ni < 4; ++ni) {
        const int col = wn * 64 + ni * 16 + (lane & 15);
        bfr[ni] = *(const bf16x8*)(bb + ((col * 128 + ks * 64 + (lane >> 4) * 16) ^ ((col & 7) << 4)));
      }
#pragma unroll
      for (int mi = 0; mi < 4; ++mi)
#pragma unroll
        for (int ni = 0; ni < 4; ++ni)
          acc[mi][ni] = __builtin_amdgcn_mfma_f32_16x16x32_bf16(af[mi], bfr[ni], acc[mi][ni], 0, 0, 0);
    }
    __builtin_amdgcn_s_barrier();   // reads of buf[cur] done before its restage next iter
  }

#pragma unroll
  for (int mi = 0; mi < 4; ++mi)
#pragma unroll
    for (int r = 0; r < 4; ++r) {
      const int row = wm * 64 + mi * 16 + (lane >> 4) * 4 + r;
#pragma unroll
      for (int ni = 0; ni < 4; ++ni) {
        const int col = wn * 64 + ni * 16 + (lane & 15);
        out[(size_t)(m0 + row) * DM + n0 + col] = acc[mi][ni][r];
      }
    }
}

extern "C" void kernel_launch(void* const* d_in, const int* in_sizes, int n_in,
                              void* d_out, int out_size, void* d_ws, size_t ws_size,
                              hipStream_t stream) {
  const float* x   = (const float*)d_in[0];
  const float* c1  = (const float*)d_in[1];
  const float* sb1 = (const float*)d_in[2];
  const float* sp1 = (const float*)d_in[3];
  const float* c2  = (const float*)d_in[4];
  const float* sb2 = (const float*)d_in[5];
  const float* sp2 = (const float*)d_in[6];
  float* out = (float*)d_out;

  unsigned short* w1t = (unsigned short*)d_ws;            // 128*8192   = 2 MB
  unsigned short* w2t = w1t + (size_t)HID * K1;           // 1024*1024  = 2 MB
  unsigned short* a2  = w2t + (size_t)DM * K2;            // 16384*1024 = 32 MB
  float*          yp  = (float*)(a2 + (size_t)NROW * K2); // 2*16384*128= 16 MB

  kan_prep_w1<<<512, 256, 0, stream>>>(c1, sb1, sp1, w1t);
  kan_prep_w2<<<512, 256, 0, stream>>>(c2, sb2, sp2, w2t);
  kan_gemm1<<<512, 512, 0, stream>>>(x, w1t, yp);
  kan_combine<<<NROW * HID / 256, 256, 0, stream>>>(yp, a2);
  kan_gemm2<<<(NROW / 128) * (DM / 128), 256, 0, stream>>>(a2, w2t, out);
}

// Round 7
// 135.750 us; speedup vs baseline: 1.3273x; 1.3273x over previous
//
#include <hip/hip_runtime.h>
#include <stdint.h>

typedef float f32x4 __attribute__((ext_vector_type(4)));
typedef __bf16 bf16x8 __attribute__((ext_vector_type(8)));
typedef __bf16 bf16x2 __attribute__((ext_vector_type(2)));
typedef unsigned short ushort4v __attribute__((ext_vector_type(4)));

#define NROW 16384
#define DM   1024
#define HID  128
#define K1   8192   // DM*8 features
#define K2   1024   // HID*8 features
#define KSPLIT 4

__device__ __forceinline__ unsigned short f2bf(float f) {
  unsigned u = __builtin_bit_cast(unsigned, f);
  u += 0x7fffu + ((u >> 16) & 1u);
  return (unsigned short)(u >> 16);
}

__device__ __forceinline__ uint32_t pk2(float lo, float hi) {
  bf16x2 v;
  v[0] = (__bf16)lo;           // pairs into v_cvt_pk_bf16_f32
  v[1] = (__bf16)hi;
  return __builtin_bit_cast(uint32_t, v);
}

__device__ __forceinline__ void g2l16(const void* g, void* l) {
  __builtin_amdgcn_global_load_lds(
      (const __attribute__((address_space(1))) unsigned int*)g,
      (__attribute__((address_space(3))) unsigned int*)l, 16, 0, 0);
}

// 8-feature expansion: [silu_hi, B0..B5, silu_lo].
// Uniform cubic B-spline, knots g_j=(j-3)*(2/3)-1 (j=0..9). Cell c=floor((v+3)*1.5),
// u=frac. Active bases B_g = P_{c-g}, g=c-3..c. Scatter [p3,p2,p1,p0] (bf16 slots,
// slot0=p3) into slots 1..6 of a 128-bit value via shift by (c-2)*16 bits.
// c clamped to [-1,9]: out-of-grid -> all-zero B (matches reference recursion).
__device__ __forceinline__ bf16x8 expand8(float v) {
  const float t = (v + 3.0f) * 1.5f;
  const float cf = floorf(t);
  const float u = t - cf;
  int c = (int)cf;
  c = c < -1 ? -1 : c;
  c = c > 9 ? 9 : c;
  const float u2 = u * u, u3 = u2 * u, omu = 1.0f - u;
  const float p0 = u3 * (1.0f / 6.0f);
  float p1 = __builtin_fmaf(0.5f, u, 1.0f / 6.0f);
  p1 = __builtin_fmaf(0.5f, u2, p1);
  p1 = __builtin_fmaf(-0.5f, u3, p1);
  float p2 = __builtin_fmaf(0.5f, u3, 4.0f / 6.0f);
  p2 = p2 - u2;
  const float p3 = (omu * omu) * (omu * (1.0f / 6.0f));
  const uint64_t W = (uint64_t)pk2(p3, p2) | ((uint64_t)pk2(p1, p0) << 32);
  const int sa = (c - 2) * 16;                 // in [-48, 112]
  const int sl = sa & 63;
  const uint64_t t1 = W << sl;
  const uint64_t t2 = (W >> (63 - sl)) >> 1;   // == W >> (64-sl), defined at sl=0
  const uint64_t t3 = W >> ((-sa) & 63);
  const uint64_t L = sa < 0 ? t3 : (sa < 64 ? t1 : 0);
  const uint64_t H = sa < 0 ? 0  : (sa < 64 ? t2 : t1);
  const float e = __expf(-v);
  const float s = v * __builtin_amdgcn_rcpf(1.0f + e);   // silu (fast rcp)
  const uint32_t su = __builtin_bit_cast(uint32_t, s);
  const uint32_t shf_bits = su & 0xffff0000u;            // truncate-split: hi part
  const float slo_f = s - __builtin_bit_cast(float, shf_bits);
  const uint32_t slo = (uint32_t)__builtin_bit_cast(unsigned short, (__bf16)slo_f);
  const uint32_t w0 = ((uint32_t)L & 0xffff0000u) | (shf_bits >> 16);
  const uint32_t w1 = (uint32_t)(L >> 32);
  const uint32_t w2 = (uint32_t)H;
  const uint32_t w3 = ((uint32_t)(H >> 32) & 0xffffu) | (slo << 16);
  union { uint4 q; bf16x8 b; } r;
  r.q = (uint4){w0, w1, w2, w3};
  return r.b;
}

// ---- weight prep: W1T[o][i*8+c] bf16, c0=scale_base (dup at c7), c1..6=coef*sp
__global__ void kan_prep_w1(const float* __restrict__ c1, const float* __restrict__ sb1,
                            const float* __restrict__ sp1, unsigned short* __restrict__ w1t) {
  const int t = blockIdx.x * 256 + threadIdx.x;     // 131072 threads
  const int o = t >> 10, i = t & 1023;
  const float sb = sb1[i * HID + o], sp = sp1[i * HID + o];
  const float* cf = c1 + (size_t)(i * HID + o) * 6;
  union { uint4 u; unsigned short h[8]; } r;
  const unsigned short b = f2bf(sb);
  r.h[0] = b; r.h[7] = b;
#pragma unroll
  for (int g = 0; g < 6; ++g) r.h[g + 1] = f2bf(cf[g] * sp);
  *(uint4*)(w1t + (size_t)o * K1 + i * 8) = r.u;
}

__global__ void kan_prep_w2(const float* __restrict__ c2, const float* __restrict__ sb2,
                            const float* __restrict__ sp2, unsigned short* __restrict__ w2t) {
  const int t = blockIdx.x * 256 + threadIdx.x;     // 131072 threads
  const int o = t >> 7, i = t & 127;
  const float sb = sb2[i * DM + o], sp = sp2[i * DM + o];
  const float* cf = c2 + (size_t)(i * DM + o) * 6;
  union { uint4 u; unsigned short h[8]; } r;
  const unsigned short b = f2bf(sb);
  r.h[0] = b; r.h[7] = b;
#pragma unroll
  for (int g = 0; g < 6; ++g) r.h[g + 1] = f2bf(cf[g] * sp);
  *(uint4*)(w2t + (size_t)o * K2 + i * 8) = r.u;
}

// ---- layer 1: fused expand(x) -> GEMM partial -> yq[kh] (bf16)
// BM=128, BN=128(full), BK=64, K-split 4. grid 512 = 128 mt x 4 kh, 512 thr
// -> 2 blocks/CU (LDS 32KB, VGPR<=128), 16 waves/CU with INDEPENDENT barriers.
// 8 waves: wk=w>>2 K-half-of-tile, wave-tile 64x64 (acc 4x4). B (W1T, L2-hot)
// loaded to VGPRs for the CURRENT tile; expansion VALU covers L2 latency.
__global__ __launch_bounds__(512, 4) void kan_gemm1(
    const float* __restrict__ x, const unsigned short* __restrict__ w1t,
    unsigned short* __restrict__ yq) {
  __shared__ __align__(16) char lds[32768];   // A dbuf 2x16KB; epilogue reuses
  const int tid = threadIdx.x;
  const int lane = tid & 63, w = tid >> 6;
  const int wk = w >> 2, wm = (w >> 1) & 1, wn = w & 1;
  const int mt = blockIdx.x >> 2, kh = blockIdx.x & 3;
  const int m0 = mt * 128;
  const int arow = tid >> 2, acs = (tid & 3) * 2;   // 2 expands/thread/tile

  f32x4 acc[4][4];
#pragma unroll
  for (int a = 0; a < 4; ++a)
#pragma unroll
    for (int b = 0; b < 4; ++b) acc[a][b] = (f32x4){0.f, 0.f, 0.f, 0.f};

  // B fragment base: rows bo+16*ni, k = kh*2048 + kt*64 + wk*32 + (lane>>4)*8
  const int bo = wn * 64 + (lane & 15);
  const unsigned short* bp = w1t + (size_t)bo * K1 + kh * 2048 + wk * 32 + (lane >> 4) * 8;

  // hoisted LDS addresses (thread-constant; buffer toggle = +16384).
  // NOTE: the +16 column step must be applied BEFORE the XOR (bit-4/5 carry
  // bug otherwise: for odd arow the swizzled +16 carries into bit 5).
  const int wraw = arow * 128 + acs * 16;
  const int wsw = (arow & 7) << 4;
  char* wa0 = lds + (wraw ^ wsw);
  char* wa1 = lds + ((wraw + 16) ^ wsw);
  const char* ra[4];
#pragma unroll
  for (int mi = 0; mi < 4; ++mi) {
    const int row = wm * 64 + mi * 16 + (lane & 15);
    ra[mi] = lds + ((row * 128 + wk * 64 + (lane >> 4) * 16) ^ ((row & 7) << 4));
  }
  const float* xrow = x + (size_t)(m0 + arow) * DM + kh * 256 + acs;

  bf16x8 b[4], af[4];
  const int NT = 32;

  // prologue: stage tile 0 into buf0, preload x for tile 1
  {
    float2 xv0 = *(const float2*)xrow;
    *(bf16x8*)wa0 = expand8(xv0.x);
    *(bf16x8*)wa1 = expand8(xv0.y);
  }
  float2 xv = *(const float2*)(xrow + 8);
  __syncthreads();

  for (int kt = 0; kt < NT; ++kt) {
    const int cur = kt & 1;
    // B for CURRENT tile; L2 latency hides under the expansion below
#pragma unroll
    for (int ni = 0; ni < 4; ++ni)
      b[ni] = *(const bf16x8*)(bp + (size_t)ni * 16 * K1 + kt * 64);
    if (kt + 1 < NT) {
      const int nb = (cur ^ 1) * 16384;
      *(bf16x8*)(wa0 + nb) = expand8(xv.x);
      *(bf16x8*)(wa1 + nb) = expand8(xv.y);
      xv = *(const float2*)(xrow + ((kt + 2 < NT) ? kt + 2 : NT - 1) * 8);
    }
#pragma unroll
    for (int mi = 0; mi < 4; ++mi)
      af[mi] = *(const bf16x8*)(ra[mi] + cur * 16384);
#pragma unroll
    for (int mi = 0; mi < 4; ++mi)
#pragma unroll
      for (int ni = 0; ni < 4; ++ni)
        acc[mi][ni] = __builtin_amdgcn_mfma_f32_16x16x32_bf16(af[mi], b[ni], acc[mi][ni], 0, 0, 0);
    __syncthreads();
  }

  // cross-wk reduce, 2 rounds reusing the 32KB A-buffers.
  // pairs: (0,4),(1,5) then (2,6),(3,7)  [wave w and w+4 share (wm,wn)]
  unsigned short* yb = yq + (size_t)kh * NROW * HID;
#pragma unroll
  for (int rnd = 0; rnd < 2; ++rnd) {
    const int src0 = 4 + rnd * 2;               // source waves (wk=1)
    if (w == src0 || w == src0 + 1) {
      char* r = lds + (w - src0) * 16384;
#pragma unroll
      for (int mi = 0; mi < 4; ++mi)
#pragma unroll
        for (int ni = 0; ni < 4; ++ni)
          *(f32x4*)(r + (mi * 4 + ni) * 1024 + lane * 16) = acc[mi][ni];
    }
    __syncthreads();
    const int snk0 = rnd * 2;                   // sink waves (wk=0)
    if (w == snk0 || w == snk0 + 1) {
      const char* r = lds + (w - snk0) * 16384;
#pragma unroll
      for (int mi = 0; mi < 4; ++mi)
#pragma unroll
        for (int ni = 0; ni < 4; ++ni) {
          f32x4 o = *(const f32x4*)(r + (mi * 4 + ni) * 1024 + lane * 16);
          o += acc[mi][ni];
          const int col = wn * 64 + ni * 16 + (lane & 15);
#pragma unroll
          for (int rr = 0; rr < 4; ++rr) {
            const int row = wm * 64 + mi * 16 + (lane >> 4) * 4 + rr;
            yb[(size_t)(m0 + row) * HID + col] = __builtin_bit_cast(unsigned short, (__bf16)o[rr]);
          }
        }
    }
    __syncthreads();
  }
}

// ---- combine 4 K-quarters (bf16) + expand y1 -> a2 (bf16 features for layer 2)
__global__ void kan_combine(const unsigned short* __restrict__ yq, unsigned short* __restrict__ a2) {
  const size_t i4 = ((size_t)blockIdx.x * 256 + threadIdx.x) * 4;   // 2,097,152 elems
  float v[4] = {0.f, 0.f, 0.f, 0.f};
#pragma unroll
  for (int h = 0; h < KSPLIT; ++h) {
    ushort4v q = *(const ushort4v*)(yq + (size_t)h * NROW * HID + i4);
#pragma unroll
    for (int j = 0; j < 4; ++j)
      v[j] += __builtin_bit_cast(float, (uint32_t)q[j] << 16);
  }
#pragma unroll
  for (int j = 0; j < 4; ++j)
    *(bf16x8*)(a2 + (i4 + j) * 8) = expand8(v[j]);
}

// ---- layer 2: plain bf16 GEMM (16384x1024) @ (1024x1024)^T -> fp32 out
// BM=BN=128, BK=64, counted-vmcnt pipeline (prefetch in flight across barrier).
__global__ __launch_bounds__(256, 2) void kan_gemm2(
    const unsigned short* __restrict__ a2, const unsigned short* __restrict__ w2t,
    float* __restrict__ out) {
  __shared__ __align__(16) unsigned short lds[2 * 16384];
  const int tid = threadIdx.x;
  const int lane = tid & 63, w = tid >> 6;
  const int wm = w >> 1, wn = w & 1;
  const int mt = blockIdx.x & 127, nt = blockIdx.x >> 7;  // mt fastest: A-panel sharers on same XCD
  const int m0 = mt * 128, n0 = nt * 128;

  f32x4 acc[4][4];
#pragma unroll
  for (int a = 0; a < 4; ++a)
#pragma unroll
    for (int b = 0; b < 4; ++b) acc[a][b] = (f32x4){0.f, 0.f, 0.f, 0.f};

  auto stage = [&](int kt, int buf) {      // 8 g2l per wave
#pragma unroll
    for (int q = 0; q < 4; ++q) {
      const int r = (w * 4 + q) * 8 + (lane >> 3);
      const int slot = (lane & 7) ^ (lane >> 3);
      g2l16(a2 + (size_t)(m0 + r) * K2 + kt * 64 + slot * 8,
            (char*)lds + buf * 32768 + (w * 4 + q) * 1024);
      g2l16(w2t + (size_t)(n0 + r) * K2 + kt * 64 + slot * 8,
            (char*)lds + buf * 32768 + 16384 + (w * 4 + q) * 1024);
    }
  };

  stage(0, 0);
  for (int kt = 0; kt < 16; ++kt) {
    const int cur = kt & 1;
    if (kt + 1 < 16) {
      stage(kt + 1, cur ^ 1);
      asm volatile("s_waitcnt vmcnt(8)" ::: "memory");   // wait tile kt only
    } else {
      asm volatile("s_waitcnt vmcnt(0)" ::: "memory");
    }
    __builtin_amdgcn_sched_barrier(0);
    __builtin_amdgcn_s_barrier();                        // tile kt in LDS for all waves
    const char* ab = (const char*)lds + cur * 32768;
    const char* bb = ab + 16384;
#pragma unroll
    for (int ks = 0; ks < 2; ++ks) {
      bf16x8 af[4], bfr[4];
#pragma unroll
      for (int mi = 0; mi < 4; ++mi) {
        const int row = wm * 64 + mi * 16 + (lane & 15);
        af[mi] = *(const bf16x8*)(ab + ((row * 128 + ks * 64 + (lane >> 4) * 16) ^ ((row & 7) << 4)));
      }
#pragma unroll
      for (int ni = 0; ni < 4; ++ni) {
        const int col = wn * 64 + ni * 16 + (lane & 15);
        bfr[ni] = *(const bf16x8*)(bb + ((col * 128 + ks * 64 + (lane >> 4) * 16) ^ ((col & 7) << 4)));
      }
#pragma unroll
      for (int mi = 0; mi < 4; ++mi)
#pragma unroll
        for (int ni = 0; ni < 4; ++ni)
          acc[mi][ni] = __builtin_amdgcn_mfma_f32_16x16x32_bf16(af[mi], bfr[ni], acc[mi][ni], 0, 0, 0);
    }
    __builtin_amdgcn_s_barrier();   // reads of buf[cur] done before its restage next iter
  }

#pragma unroll
  for (int mi = 0; mi < 4; ++mi)
#pragma unroll
    for (int r = 0; r < 4; ++r) {
      const int row = wm * 64 + mi * 16 + (lane >> 4) * 4 + r;
#pragma unroll
      for (int ni = 0; ni < 4; ++ni) {
        const int col = wn * 64 + ni * 16 + (lane & 15);
        out[(size_t)(m0 + row) * DM + n0 + col] = acc[mi][ni][r];
      }
    }
}

extern "C" void kernel_launch(void* const* d_in, const int* in_sizes, int n_in,
                              void* d_out, int out_size, void* d_ws, size_t ws_size,
                              hipStream_t stream) {
  const float* x   = (const float*)d_in[0];
  const float* c1  = (const float*)d_in[1];
  const float* sb1 = (const float*)d_in[2];
  const float* sp1 = (const float*)d_in[3];
  const float* c2  = (const float*)d_in[4];
  const float* sb2 = (const float*)d_in[5];
  const float* sp2 = (const float*)d_in[6];
  float* out = (float*)d_out;

  unsigned short* w1t = (unsigned short*)d_ws;            // 128*8192   = 2 MB
  unsigned short* w2t = w1t + (size_t)HID * K1;           // 1024*1024  = 2 MB
  unsigned short* a2  = w2t + (size_t)DM * K2;            // 16384*1024 = 32 MB
  unsigned short* yq  = a2 + (size_t)NROW * K2;           // 4*16384*128*2B = 16 MB

  kan_prep_w1<<<512, 256, 0, stream>>>(c1, sb1, sp1, w1t);
  kan_prep_w2<<<512, 256, 0, stream>>>(c2, sb2, sp2, w2t);
  kan_gemm1<<<512, 512, 0, stream>>>(x, w1t, yq);
  kan_combine<<<NROW * HID / 1024, 256, 0, stream>>>(yq, a2);
  kan_gemm2<<<(NROW / 128) * (DM / 128), 256, 0, stream>>>(a2, w2t, out);
}